// Round 1
// baseline (901.949 us; speedup 1.0000x reference)
//
#include <hip/hip_runtime.h>

#define N_NODES 100000
#define N_EDGES 400000
#define N_GRAPHS 2000
#define F_IN 74
#define HID 64
#define NHEAD 4
#define HID4 256
#define OUT_DIM 128
#define NODES_PER_G 50

// ---------------------------------------------------------------- CSR build
__global__ __launch_bounds__(256) void k_count(const int* __restrict__ dst,
                                               int* __restrict__ off) {
  int e = blockIdx.x * 256 + threadIdx.x;
  if (e < N_EDGES) atomicAdd(&off[dst[e] + 1], 1);
}

// inclusive scan, hierarchical: 1024 elems per block
__global__ __launch_bounds__(256) void k_scan1(int* __restrict__ data, int n,
                                               int* __restrict__ blksum) {
  __shared__ int sh[256];
  int t = threadIdx.x;
  int base = blockIdx.x * 1024 + t * 4;
  int v0 = (base + 0 < n) ? data[base + 0] : 0;
  int v1 = (base + 1 < n) ? data[base + 1] : 0;
  int v2 = (base + 2 < n) ? data[base + 2] : 0;
  int v3 = (base + 3 < n) ? data[base + 3] : 0;
  v1 += v0; v2 += v1; v3 += v2;
  int tot = v3;
  sh[t] = tot;
  __syncthreads();
  for (int o = 1; o < 256; o <<= 1) {
    int x = (t >= o) ? sh[t - o] : 0;
    __syncthreads();
    sh[t] += x;
    __syncthreads();
  }
  int excl = sh[t] - tot;
  if (base + 0 < n) data[base + 0] = v0 + excl;
  if (base + 1 < n) data[base + 1] = v1 + excl;
  if (base + 2 < n) data[base + 2] = v2 + excl;
  if (base + 3 < n) data[base + 3] = v3 + excl;
  if (t == 255) blksum[blockIdx.x] = sh[255];
}

__global__ __launch_bounds__(256) void k_scan2(int* __restrict__ blksum, int nb) {
  __shared__ int sh[256];
  int t = threadIdx.x;
  sh[t] = (t < nb) ? blksum[t] : 0;
  __syncthreads();
  for (int o = 1; o < 256; o <<= 1) {
    int x = (t >= o) ? sh[t - o] : 0;
    __syncthreads();
    sh[t] += x;
    __syncthreads();
  }
  if (t < nb) blksum[t] = sh[t];
}

__global__ __launch_bounds__(256) void k_scan3(int* __restrict__ data, int n,
                                               const int* __restrict__ blksum) {
  int b = blockIdx.x;
  if (b == 0) return;
  int add = blksum[b - 1];
  int base = b * 1024 + threadIdx.x * 4;
  for (int j = 0; j < 4; ++j)
    if (base + j < n) data[base + j] += add;
}

__global__ __launch_bounds__(256) void k_scatter(const int* __restrict__ dst,
                                                 const int* __restrict__ off,
                                                 int* __restrict__ cursor,
                                                 int* __restrict__ eidx) {
  int e = blockIdx.x * 256 + threadIdx.x;
  if (e >= N_EDGES) return;
  int d = dst[e];
  int pos = off[d] + atomicAdd(&cursor[d], 1);
  eidx[pos] = e;
}

// deterministic edge order within each segment (atomic scatter order varies)
__global__ __launch_bounds__(256) void k_sortseg(const int* __restrict__ off,
                                                 int* __restrict__ eidx) {
  int n = blockIdx.x * 256 + threadIdx.x;
  if (n >= N_NODES) return;
  int beg = off[n], end = off[n + 1];
  for (int i = beg + 1; i < end; ++i) {
    int key = eidx[i];
    int j = i - 1;
    while (j >= beg && eidx[j] > key) { eidx[j + 1] = eidx[j]; --j; }
    eidx[j + 1] = key;
  }
}

// ---------------------------------------------------------------- encoder
__global__ __launch_bounds__(256) void k_encoder(const float* __restrict__ nf,
                                                 const float* __restrict__ W,
                                                 const float* __restrict__ b,
                                                 float* __restrict__ h) {
  __shared__ float Ws[F_IN * HID];
  int t = threadIdx.x;
  for (int i = t; i < F_IN * HID; i += 256) Ws[i] = W[i];
  __syncthreads();
  int idx = blockIdx.x * 256 + t;
  int n = idx >> 6;
  int c = idx & 63;
  if (n >= N_NODES) return;
  float acc = b[c];
  const float* row = nf + (size_t)n * F_IN;
  for (int k = 0; k < F_IN; ++k) acc = fmaf(row[k], Ws[k * HID + c], acc);
  h[(size_t)n * HID + c] = acc;
}

// ---------------------------------------------------------------- z GEMM
// C[N,256] = A[N,K] @ W[K,256]
template <int K>
__global__ __launch_bounds__(256) void k_gemm(const float* __restrict__ A,
                                              const float* __restrict__ W,
                                              float* __restrict__ C, int n_rows) {
  __shared__ float As[16][68];  // transposed A tile, padded
  __shared__ float Ws[16][64];
  int bm = blockIdx.x * 64;
  int bn = blockIdx.y * 64;
  int t = threadIdx.x;
  int tx = t & 15;   // col group
  int ty = t >> 4;   // row group
  float acc[4][4] = {};
  for (int k0 = 0; k0 < K; k0 += 16) {
    {  // A tile: 64 rows x 16 cols
      int r = t >> 2;
      int c4 = (t & 3) * 4;
      int gr = bm + r;
      float4 v = make_float4(0.f, 0.f, 0.f, 0.f);
      if (gr < n_rows) v = *(const float4*)(A + (size_t)gr * K + k0 + c4);
      As[c4 + 0][r] = v.x; As[c4 + 1][r] = v.y;
      As[c4 + 2][r] = v.z; As[c4 + 3][r] = v.w;
    }
    {  // W tile: 16 rows x 64 cols
      int r = t >> 4;
      int c4 = (t & 15) * 4;
      float4 v = *(const float4*)(W + (size_t)(k0 + r) * HID4 + bn + c4);
      *(float4*)&Ws[r][c4] = v;
    }
    __syncthreads();
#pragma unroll
    for (int kk = 0; kk < 16; ++kk) {
      float4 a = *(const float4*)&As[kk][ty * 4];
      float4 bq = *(const float4*)&Ws[kk][tx * 4];
      float av[4] = {a.x, a.y, a.z, a.w};
      float bv[4] = {bq.x, bq.y, bq.z, bq.w};
#pragma unroll
      for (int i = 0; i < 4; ++i)
#pragma unroll
        for (int j = 0; j < 4; ++j) acc[i][j] = fmaf(av[i], bv[j], acc[i][j]);
    }
    __syncthreads();
  }
  for (int i = 0; i < 4; ++i) {
    int gr = bm + ty * 4 + i;
    if (gr >= n_rows) continue;
    float4 v = make_float4(acc[i][0], acc[i][1], acc[i][2], acc[i][3]);
    *(float4*)(C + (size_t)gr * HID4 + bn + tx * 4) = v;
  }
}

// ---------------------------------------------------------------- el/er
__global__ __launch_bounds__(256) void k_el_er(const float* __restrict__ z,
                                               const float* __restrict__ al,
                                               const float* __restrict__ ar,
                                               float* __restrict__ el,
                                               float* __restrict__ er) {
  int wave = (blockIdx.x * 256 + threadIdx.x) >> 6;
  int lane = threadIdx.x & 63;
  if (wave >= N_NODES) return;
  int h = lane >> 4;
  int c = lane * 4;  // c == h*64 + (lane%16)*4, matches flat [H,HID]
  float4 zv = *(const float4*)(z + (size_t)wave * HID4 + c);
  float4 av = *(const float4*)(al + c);
  float4 rv = *(const float4*)(ar + c);
  float pl = zv.x * av.x + zv.y * av.y + zv.z * av.z + zv.w * av.w;
  float pr = zv.x * rv.x + zv.y * rv.y + zv.z * rv.z + zv.w * rv.w;
  for (int o = 1; o < 16; o <<= 1) {
    pl += __shfl_xor(pl, o, 64);
    pr += __shfl_xor(pr, o, 64);
  }
  if ((lane & 15) == 0) {
    el[(size_t)wave * NHEAD + h] = pl;
    er[(size_t)wave * NHEAD + h] = pr;
  }
}

// ------------------------------------------------- fused edge softmax + agg
__global__ __launch_bounds__(256) void k_agg(const float* __restrict__ z,
                                             const float* __restrict__ el,
                                             const float* __restrict__ er,
                                             const int* __restrict__ off,
                                             const int* __restrict__ eidx,
                                             const int* __restrict__ src,
                                             const float* __restrict__ bias,
                                             float* __restrict__ out) {
  int n = (blockIdx.x * 256 + threadIdx.x) >> 6;  // one wave per dst node
  int lane = threadIdx.x & 63;
  if (n >= N_NODES) return;
  int h = lane >> 4;
  int c = lane * 4;
  int beg = off[n], end = off[n + 1];
  float erh = er[(size_t)n * NHEAD + h];
  float m = -1e30f, s = 0.f;
  float ax = 0.f, ay = 0.f, az = 0.f, aw = 0.f;
  for (int p = beg; p < end; ++p) {
    int e = eidx[p];
    int sn = src[e];
    float eh = el[(size_t)sn * NHEAD + h] + erh;
    eh = eh >= 0.f ? eh : 0.2f * eh;
    float nm = fmaxf(m, eh);
    float scale = expf(m - nm);
    float pexp = expf(eh - nm);
    s = s * scale + pexp;
    float4 zv = *(const float4*)(z + (size_t)sn * HID4 + c);
    ax = ax * scale + pexp * zv.x;
    ay = ay * scale + pexp * zv.y;
    az = az * scale + pexp * zv.z;
    aw = aw * scale + pexp * zv.w;
    m = nm;
  }
  float inv = (s > 0.f) ? 1.f / s : 0.f;
  float4 b4 = *(const float4*)(bias + c);
  float4 o;
  o.x = fmaxf(ax * inv + b4.x, 0.f);
  o.y = fmaxf(ay * inv + b4.y, 0.f);
  o.z = fmaxf(az * inv + b4.z, 0.f);
  o.w = fmaxf(aw * inv + b4.w, 0.f);
  *(float4*)(out + (size_t)n * HID4 + c) = o;
}

// ---------------------------------------------------------------- readout
__global__ __launch_bounds__(256) void k_pool_mlp(const float* __restrict__ h,
                                                  const float* __restrict__ r1W,
                                                  const float* __restrict__ r1b,
                                                  const float* __restrict__ r2W,
                                                  const float* __restrict__ r2b,
                                                  float* __restrict__ out) {
  __shared__ float pooled[3 * HID4];
  __shared__ float mid[HID];
  int g = blockIdx.x;
  int t = threadIdx.x;
  const float* base = h + (size_t)g * NODES_PER_G * HID4;
  float sum = 0.f, mx = -1e30f;
  for (int i = 0; i < NODES_PER_G; ++i) {
    float v = base[(size_t)i * HID4 + t];
    sum += v;
    mx = fmaxf(mx, v);
  }
  pooled[t] = sum / (float)NODES_PER_G;
  pooled[HID4 + t] = mx;
  pooled[2 * HID4 + t] = sum;
  __syncthreads();
  if (t < HID) {
    float acc = r1b[t];
    for (int k = 0; k < 3 * HID4; ++k) acc = fmaf(pooled[k], r1W[k * HID + t], acc);
    mid[t] = fmaxf(acc, 0.f);
  }
  __syncthreads();
  if (t < OUT_DIM) {
    float acc = r2b[t];
    for (int k = 0; k < HID; ++k) acc = fmaf(mid[k], r2W[k * OUT_DIM + t], acc);
    out[(size_t)g * OUT_DIM + t] = acc;
  }
}

// ---------------------------------------------------------------- launch
extern "C" void kernel_launch(void* const* d_in, const int* in_sizes, int n_in,
                              void* d_out, int out_size, void* d_ws, size_t ws_size,
                              hipStream_t stream) {
  const float* node_feat = (const float*)d_in[0];
  const int* src = (const int*)d_in[1];
  const int* dst = (const int*)d_in[2];
  const float* enc_W = (const float*)d_in[4];
  const float* enc_b = (const float*)d_in[5];
  const float* Wl[3] = {(const float*)d_in[6], (const float*)d_in[10], (const float*)d_in[14]};
  const float* all[3] = {(const float*)d_in[7], (const float*)d_in[11], (const float*)d_in[15]};
  const float* arl[3] = {(const float*)d_in[8], (const float*)d_in[12], (const float*)d_in[16]};
  const float* bl[3] = {(const float*)d_in[9], (const float*)d_in[13], (const float*)d_in[17]};
  const float* r1W = (const float*)d_in[18];
  const float* r1b = (const float*)d_in[19];
  const float* r2W = (const float*)d_in[20];
  const float* r2b = (const float*)d_in[21];
  float* out = (float*)d_out;

  char* p = (char*)d_ws;
  auto alloc = [&](size_t bytes) {
    void* r = (void*)p;
    p += (bytes + 255) & ~(size_t)255;
    return r;
  };
  int* off = (int*)alloc((N_NODES + 1) * sizeof(int));
  int* cursor = (int*)alloc(N_NODES * sizeof(int));
  int* eidx = (int*)alloc(N_EDGES * sizeof(int));
  int* blksum = (int*)alloc(256 * sizeof(int));
  float* el = (float*)alloc((size_t)N_NODES * NHEAD * sizeof(float));
  float* er = (float*)alloc((size_t)N_NODES * NHEAD * sizeof(float));
  float* P = (float*)alloc((size_t)N_NODES * HID4 * sizeof(float));
  float* Q = (float*)alloc((size_t)N_NODES * HID4 * sizeof(float));

  // ---- CSR build (deterministic via per-segment sort)
  hipMemsetAsync(off, 0, (N_NODES + 1) * sizeof(int), stream);
  hipMemsetAsync(cursor, 0, N_NODES * sizeof(int), stream);
  k_count<<<(N_EDGES + 255) / 256, 256, 0, stream>>>(dst, off);
  const int SCAN_N = N_NODES + 1;
  const int NB = (SCAN_N + 1023) / 1024;  // 98
  k_scan1<<<NB, 256, 0, stream>>>(off, SCAN_N, blksum);
  k_scan2<<<1, 256, 0, stream>>>(blksum, NB);
  k_scan3<<<NB, 256, 0, stream>>>(off, SCAN_N, blksum);
  k_scatter<<<(N_EDGES + 255) / 256, 256, 0, stream>>>(dst, off, cursor, eidx);
  k_sortseg<<<(N_NODES + 255) / 256, 256, 0, stream>>>(off, eidx);

  // ---- encoder: P[:, :64] = nf @ enc_W + enc_b
  k_encoder<<<((size_t)N_NODES * HID + 255) / 256, 256, 0, stream>>>(node_feat, enc_W, enc_b, P);

  // ---- 3 GAT layers, ping-pong P<->Q (z lives in Q, h ping-pongs in P)
  dim3 ggrid((N_NODES + 63) / 64, HID4 / 64);
  for (int l = 0; l < 3; ++l) {
    if (l == 0)
      k_gemm<HID><<<ggrid, 256, 0, stream>>>(P, Wl[0], Q, N_NODES);
    else
      k_gemm<HID4><<<ggrid, 256, 0, stream>>>(P, Wl[l], Q, N_NODES);
    k_el_er<<<(N_NODES + 3) / 4, 256, 0, stream>>>(Q, all[l], arl[l], el, er);
    k_agg<<<(N_NODES + 3) / 4, 256, 0, stream>>>(Q, el, er, off, eidx, src, bl[l], P);
  }

  // ---- readout
  k_pool_mlp<<<N_GRAPHS, 256, 0, stream>>>(P, r1W, r1b, r2W, r2b, out);
}

// Round 2
// 597.246 us; speedup vs baseline: 1.5102x; 1.5102x over previous
//
#include <hip/hip_runtime.h>

#define N_NODES 100000
#define N_EDGES 400000
#define N_GRAPHS 2000
#define F_IN 74
#define HID 64
#define NHEAD 4
#define HID4 256
#define OUT_DIM 128
#define NODES_PER_G 50

typedef __attribute__((ext_vector_type(8))) short short8;
typedef __attribute__((ext_vector_type(4))) float f32x4;

__device__ inline ushort f2bf(float f) {
  union { float f; unsigned u; } v; v.f = f;
  unsigned u = v.u;
  return (ushort)((u + 0x7FFFu + ((u >> 16) & 1u)) >> 16);
}
__device__ inline float bf2f(ushort b) {
  union { unsigned u; float f; } v; v.u = ((unsigned)b) << 16;
  return v.f;
}

// ---------------------------------------------------------------- CSR build
__global__ __launch_bounds__(256) void k_count(const int* __restrict__ dst,
                                               int* __restrict__ off) {
  int e = blockIdx.x * 256 + threadIdx.x;
  if (e < N_EDGES) atomicAdd(&off[dst[e] + 1], 1);
}

__global__ __launch_bounds__(256) void k_scan1(int* __restrict__ data, int n,
                                               int* __restrict__ blksum) {
  __shared__ int sh[256];
  int t = threadIdx.x;
  int base = blockIdx.x * 1024 + t * 4;
  int v0 = (base + 0 < n) ? data[base + 0] : 0;
  int v1 = (base + 1 < n) ? data[base + 1] : 0;
  int v2 = (base + 2 < n) ? data[base + 2] : 0;
  int v3 = (base + 3 < n) ? data[base + 3] : 0;
  v1 += v0; v2 += v1; v3 += v2;
  int tot = v3;
  sh[t] = tot;
  __syncthreads();
  for (int o = 1; o < 256; o <<= 1) {
    int x = (t >= o) ? sh[t - o] : 0;
    __syncthreads();
    sh[t] += x;
    __syncthreads();
  }
  int excl = sh[t] - tot;
  if (base + 0 < n) data[base + 0] = v0 + excl;
  if (base + 1 < n) data[base + 1] = v1 + excl;
  if (base + 2 < n) data[base + 2] = v2 + excl;
  if (base + 3 < n) data[base + 3] = v3 + excl;
  if (t == 255) blksum[blockIdx.x] = sh[255];
}

__global__ __launch_bounds__(256) void k_scan2(int* __restrict__ blksum, int nb) {
  __shared__ int sh[256];
  int t = threadIdx.x;
  sh[t] = (t < nb) ? blksum[t] : 0;
  __syncthreads();
  for (int o = 1; o < 256; o <<= 1) {
    int x = (t >= o) ? sh[t - o] : 0;
    __syncthreads();
    sh[t] += x;
    __syncthreads();
  }
  if (t < nb) blksum[t] = sh[t];
}

__global__ __launch_bounds__(256) void k_scan3(int* __restrict__ data, int n,
                                               const int* __restrict__ blksum) {
  int b = blockIdx.x;
  if (b == 0) return;
  int add = blksum[b - 1];
  int base = b * 1024 + threadIdx.x * 4;
  for (int j = 0; j < 4; ++j)
    if (base + j < n) data[base + j] += add;
}

__global__ __launch_bounds__(256) void k_scatter(const int* __restrict__ dst,
                                                 const int* __restrict__ off,
                                                 int* __restrict__ cursor,
                                                 int* __restrict__ eidx) {
  int e = blockIdx.x * 256 + threadIdx.x;
  if (e >= N_EDGES) return;
  int d = dst[e];
  int pos = off[d] + atomicAdd(&cursor[d], 1);
  eidx[pos] = e;
}

__global__ __launch_bounds__(256) void k_sortseg(const int* __restrict__ off,
                                                 int* __restrict__ eidx) {
  int n = blockIdx.x * 256 + threadIdx.x;
  if (n >= N_NODES) return;
  int beg = off[n], end = off[n + 1];
  for (int i = beg + 1; i < end; ++i) {
    int key = eidx[i];
    int j = i - 1;
    while (j >= beg && eidx[j] > key) { eidx[j + 1] = eidx[j]; --j; }
    eidx[j + 1] = key;
  }
}

// ---------------------------------------------------------------- encoder
__global__ __launch_bounds__(256) void k_encoder(const float* __restrict__ nf,
                                                 const float* __restrict__ W,
                                                 const float* __restrict__ b,
                                                 ushort* __restrict__ hb) {
  __shared__ float Ws[F_IN * HID];
  int t = threadIdx.x;
  for (int i = t; i < F_IN * HID; i += 256) Ws[i] = W[i];
  __syncthreads();
  int idx = blockIdx.x * 256 + t;
  int n = idx >> 6;
  int c = idx & 63;
  if (n >= N_NODES) return;
  float acc = b[c];
  const float* row = nf + (size_t)n * F_IN;
  for (int k = 0; k < F_IN; ++k) acc = fmaf(row[k], Ws[k * HID + c], acc);
  hb[(size_t)n * HID + c] = f2bf(acc);
}

// ----------------------------------------------- W[K,256] -> Wt[256,K] bf16
template <int K>
__global__ __launch_bounds__(256) void k_wt(const float* __restrict__ W,
                                            ushort* __restrict__ Wt) {
  int idx = blockIdx.x * 256 + threadIdx.x;
  if (idx >= K * HID4) return;
  int k = idx >> 8;
  int n = idx & 255;
  Wt[(size_t)n * K + k] = f2bf(W[idx]);
}

// ---------------------------------------------------------- bf16 MFMA GEMM
// C[n_rows,256] (fp32) = A[n_rows,K] (bf16) @ Wt[256,K]^T (bf16)
template <int K>
__global__ __launch_bounds__(256) void k_gemm_mfma(const ushort* __restrict__ A,
                                                   const ushort* __restrict__ Bt,
                                                   float* __restrict__ C,
                                                   int n_rows) {
  __shared__ ushort As[128][40];  // [row][k], +8 pad
  __shared__ ushort Bs[128][40];  // [col][k], +8 pad
  int t = threadIdx.x;
  int lane = t & 63;
  int wid = t >> 6;
  int wr = wid >> 1, wc = wid & 1;  // 2x2 waves, each 64x64
  int brow = blockIdx.x * 128;
  int bcol = blockIdx.y * 128;

  f32x4 acc[4][4];
#pragma unroll
  for (int m = 0; m < 4; ++m)
#pragma unroll
    for (int n = 0; n < 4; ++n) acc[m][n] = (f32x4)(0.f);

  int srow = t >> 2;          // 0..63
  int soff = (t & 3) * 8;     // bf16 elems within 32-k slice
  int fr = lane & 15;
  int ko = (lane >> 4) * 8;

  for (int k0 = 0; k0 < K; k0 += 32) {
    // stage A (rows srow, srow+64) and B
    {
      int gr0 = brow + srow, gr1 = gr0 + 64;
      int4 z4 = make_int4(0, 0, 0, 0);
      int4 va0 = (gr0 < n_rows) ? *(const int4*)(A + (size_t)gr0 * K + k0 + soff) : z4;
      int4 va1 = (gr1 < n_rows) ? *(const int4*)(A + (size_t)gr1 * K + k0 + soff) : z4;
      int4 vb0 = *(const int4*)(Bt + (size_t)(bcol + srow) * K + k0 + soff);
      int4 vb1 = *(const int4*)(Bt + (size_t)(bcol + srow + 64) * K + k0 + soff);
      *(int4*)&As[srow][soff] = va0;
      *(int4*)&As[srow + 64][soff] = va1;
      *(int4*)&Bs[srow][soff] = vb0;
      *(int4*)&Bs[srow + 64][soff] = vb1;
    }
    __syncthreads();
    short8 a[4], b[4];
#pragma unroll
    for (int m = 0; m < 4; ++m) a[m] = *(const short8*)&As[wr * 64 + m * 16 + fr][ko];
#pragma unroll
    for (int n = 0; n < 4; ++n) b[n] = *(const short8*)&Bs[wc * 64 + n * 16 + fr][ko];
#pragma unroll
    for (int m = 0; m < 4; ++m)
#pragma unroll
      for (int n = 0; n < 4; ++n)
        acc[m][n] = __builtin_amdgcn_mfma_f32_16x16x32_bf16(a[m], b[n], acc[m][n], 0, 0, 0);
    __syncthreads();
  }

  int r0 = (lane >> 4) * 4;
  int cc = lane & 15;
#pragma unroll
  for (int m = 0; m < 4; ++m) {
#pragma unroll
    for (int j = 0; j < 4; ++j) {
      int row = brow + wr * 64 + m * 16 + r0 + j;
      if (row >= n_rows) continue;
#pragma unroll
      for (int n = 0; n < 4; ++n)
        C[(size_t)row * HID4 + bcol + wc * 64 + n * 16 + cc] = acc[m][n][j];
    }
  }
}

// ---------------------------------------------------------------- el/er
__global__ __launch_bounds__(256) void k_el_er(const float* __restrict__ z,
                                               const float* __restrict__ al,
                                               const float* __restrict__ ar,
                                               float* __restrict__ el,
                                               float* __restrict__ er) {
  int wave = (blockIdx.x * 256 + threadIdx.x) >> 6;
  int lane = threadIdx.x & 63;
  if (wave >= N_NODES) return;
  int h = lane >> 4;
  int c = lane * 4;
  float4 zv = *(const float4*)(z + (size_t)wave * HID4 + c);
  float4 av = *(const float4*)(al + c);
  float4 rv = *(const float4*)(ar + c);
  float pl = zv.x * av.x + zv.y * av.y + zv.z * av.z + zv.w * av.w;
  float pr = zv.x * rv.x + zv.y * rv.y + zv.z * rv.z + zv.w * rv.w;
  for (int o = 1; o < 16; o <<= 1) {
    pl += __shfl_xor(pl, o, 64);
    pr += __shfl_xor(pr, o, 64);
  }
  if ((lane & 15) == 0) {
    el[(size_t)wave * NHEAD + h] = pl;
    er[(size_t)wave * NHEAD + h] = pr;
  }
}

// ------------------------------------------------- fused edge softmax + agg
__global__ __launch_bounds__(256) void k_agg(const float* __restrict__ z,
                                             const float* __restrict__ el,
                                             const float* __restrict__ er,
                                             const int* __restrict__ off,
                                             const int* __restrict__ eidx,
                                             const int* __restrict__ src,
                                             const float* __restrict__ bias,
                                             ushort* __restrict__ outb) {
  int n = (blockIdx.x * 256 + threadIdx.x) >> 6;  // one wave per dst node
  int lane = threadIdx.x & 63;
  if (n >= N_NODES) return;
  int h = lane >> 4;
  int c = lane * 4;
  int beg = off[n], end = off[n + 1];
  float erh = er[(size_t)n * NHEAD + h];
  float m = -1e30f, s = 0.f;
  float ax = 0.f, ay = 0.f, az = 0.f, aw = 0.f;
  for (int p = beg; p < end; ++p) {
    int e = eidx[p];
    int sn = src[e];
    float eh = el[(size_t)sn * NHEAD + h] + erh;
    eh = eh >= 0.f ? eh : 0.2f * eh;
    float nm = fmaxf(m, eh);
    float scale = expf(m - nm);
    float pexp = expf(eh - nm);
    s = s * scale + pexp;
    float4 zv = *(const float4*)(z + (size_t)sn * HID4 + c);
    ax = ax * scale + pexp * zv.x;
    ay = ay * scale + pexp * zv.y;
    az = az * scale + pexp * zv.z;
    aw = aw * scale + pexp * zv.w;
    m = nm;
  }
  float inv = (s > 0.f) ? 1.f / s : 0.f;
  float4 b4 = *(const float4*)(bias + c);
  ushort4 o;
  o.x = f2bf(fmaxf(ax * inv + b4.x, 0.f));
  o.y = f2bf(fmaxf(ay * inv + b4.y, 0.f));
  o.z = f2bf(fmaxf(az * inv + b4.z, 0.f));
  o.w = f2bf(fmaxf(aw * inv + b4.w, 0.f));
  *(ushort4*)(outb + (size_t)n * HID4 + c) = o;
}

// ---------------------------------------------------------------- readout
__global__ __launch_bounds__(256) void k_pool_mlp(const ushort* __restrict__ h,
                                                  const float* __restrict__ r1W,
                                                  const float* __restrict__ r1b,
                                                  const float* __restrict__ r2W,
                                                  const float* __restrict__ r2b,
                                                  float* __restrict__ out) {
  __shared__ float pooled[3 * HID4];
  __shared__ float part[4][HID];
  __shared__ float mid[HID];
  int g = blockIdx.x;
  int t = threadIdx.x;
  const ushort* base = h + (size_t)g * NODES_PER_G * HID4;
  float sum = 0.f, mx = -1e30f;
  for (int i = 0; i < NODES_PER_G; ++i) {
    float v = bf2f(base[(size_t)i * HID4 + t]);
    sum += v;
    mx = fmaxf(mx, v);
  }
  pooled[t] = sum / (float)NODES_PER_G;
  pooled[HID4 + t] = mx;
  pooled[2 * HID4 + t] = sum;
  __syncthreads();
  {
    int o = t & 63, chunk = t >> 6;
    float acc = 0.f;
    int k0 = chunk * 192;
    for (int k = k0; k < k0 + 192; ++k) acc = fmaf(pooled[k], r1W[k * HID + o], acc);
    part[chunk][o] = acc;
  }
  __syncthreads();
  if (t < HID) {
    float acc = r1b[t] + part[0][t] + part[1][t] + part[2][t] + part[3][t];
    mid[t] = fmaxf(acc, 0.f);
  }
  __syncthreads();
  if (t < OUT_DIM) {
    float acc = r2b[t];
    for (int k = 0; k < HID; ++k) acc = fmaf(mid[k], r2W[k * OUT_DIM + t], acc);
    out[(size_t)g * OUT_DIM + t] = acc;
  }
}

// ---------------------------------------------------------------- launch
extern "C" void kernel_launch(void* const* d_in, const int* in_sizes, int n_in,
                              void* d_out, int out_size, void* d_ws, size_t ws_size,
                              hipStream_t stream) {
  const float* node_feat = (const float*)d_in[0];
  const int* src = (const int*)d_in[1];
  const int* dst = (const int*)d_in[2];
  const float* enc_W = (const float*)d_in[4];
  const float* enc_b = (const float*)d_in[5];
  const float* Wl[3] = {(const float*)d_in[6], (const float*)d_in[10], (const float*)d_in[14]};
  const float* all[3] = {(const float*)d_in[7], (const float*)d_in[11], (const float*)d_in[15]};
  const float* arl[3] = {(const float*)d_in[8], (const float*)d_in[12], (const float*)d_in[16]};
  const float* bl[3] = {(const float*)d_in[9], (const float*)d_in[13], (const float*)d_in[17]};
  const float* r1W = (const float*)d_in[18];
  const float* r1b = (const float*)d_in[19];
  const float* r2W = (const float*)d_in[20];
  const float* r2b = (const float*)d_in[21];
  float* out = (float*)d_out;

  char* p = (char*)d_ws;
  auto alloc = [&](size_t bytes) {
    void* r = (void*)p;
    p += (bytes + 255) & ~(size_t)255;
    return r;
  };
  int* off = (int*)alloc((N_NODES + 1) * sizeof(int));
  int* cursor = (int*)alloc(N_NODES * sizeof(int));
  int* eidx = (int*)alloc(N_EDGES * sizeof(int));
  int* blksum = (int*)alloc(256 * sizeof(int));
  float* el = (float*)alloc((size_t)N_NODES * NHEAD * sizeof(float));
  float* er = (float*)alloc((size_t)N_NODES * NHEAD * sizeof(float));
  float* Q = (float*)alloc((size_t)N_NODES * HID4 * sizeof(float));       // z (fp32)
  ushort* Pb = (ushort*)alloc((size_t)N_NODES * HID4 * sizeof(ushort));   // h (bf16)
  ushort* Wt = (ushort*)alloc((size_t)HID4 * HID4 * sizeof(ushort));      // W^T bf16

  // ---- CSR build (deterministic via per-segment sort)
  hipMemsetAsync(off, 0, (N_NODES + 1) * sizeof(int), stream);
  hipMemsetAsync(cursor, 0, N_NODES * sizeof(int), stream);
  k_count<<<(N_EDGES + 255) / 256, 256, 0, stream>>>(dst, off);
  const int SCAN_N = N_NODES + 1;
  const int NB = (SCAN_N + 1023) / 1024;
  k_scan1<<<NB, 256, 0, stream>>>(off, SCAN_N, blksum);
  k_scan2<<<1, 256, 0, stream>>>(blksum, NB);
  k_scan3<<<NB, 256, 0, stream>>>(off, SCAN_N, blksum);
  k_scatter<<<(N_EDGES + 255) / 256, 256, 0, stream>>>(dst, off, cursor, eidx);
  k_sortseg<<<(N_NODES + 255) / 256, 256, 0, stream>>>(off, eidx);

  // ---- encoder -> Pb (bf16, stride 64)
  k_encoder<<<((size_t)N_NODES * HID + 255) / 256, 256, 0, stream>>>(node_feat, enc_W, enc_b, Pb);

  // ---- 3 GAT layers: GEMM (Pb -> Q) ; el/er ; agg (Q -> Pb)
  dim3 ggrid((N_NODES + 127) / 128, HID4 / 128);
  for (int l = 0; l < 3; ++l) {
    if (l == 0) {
      k_wt<HID><<<(HID * HID4 + 255) / 256, 256, 0, stream>>>(Wl[0], Wt);
      k_gemm_mfma<HID><<<ggrid, 256, 0, stream>>>(Pb, Wt, Q, N_NODES);
    } else {
      k_wt<HID4><<<(HID4 * HID4 + 255) / 256, 256, 0, stream>>>(Wl[l], Wt);
      k_gemm_mfma<HID4><<<ggrid, 256, 0, stream>>>(Pb, Wt, Q, N_NODES);
    }
    k_el_er<<<(N_NODES + 3) / 4, 256, 0, stream>>>(Q, all[l], arl[l], el, er);
    k_agg<<<(N_NODES + 3) / 4, 256, 0, stream>>>(Q, el, er, off, eidx, src, bl[l], Pb);
  }

  // ---- readout
  k_pool_mlp<<<N_GRAPHS, 256, 0, stream>>>(Pb, r1W, r1b, r2W, r2b, out);
}

// Round 3
// 496.496 us; speedup vs baseline: 1.8166x; 1.2029x over previous
//
#include <hip/hip_runtime.h>

#define N_NODES 100000
#define N_EDGES 400000
#define N_GRAPHS 2000
#define F_IN 74
#define HID 64
#define NHEAD 4
#define HID4 256
#define OUT_DIM 128
#define NODES_PER_G 50

typedef __attribute__((ext_vector_type(8))) short short8;
typedef __attribute__((ext_vector_type(4))) float f32x4;

__device__ inline ushort f2bf(float f) {
  union { float f; unsigned u; } v; v.f = f;
  unsigned u = v.u;
  return (ushort)((u + 0x7FFFu + ((u >> 16) & 1u)) >> 16);
}
__device__ inline float bf2f(ushort b) {
  union { unsigned u; float f; } v; v.u = ((unsigned)b) << 16;
  return v.f;
}

// ---------------------------------------------------------------- CSR build
__global__ __launch_bounds__(256) void k_count(const int* __restrict__ dst,
                                               int* __restrict__ off) {
  int e = blockIdx.x * 256 + threadIdx.x;
  if (e < N_EDGES) atomicAdd(&off[dst[e] + 1], 1);
}

__global__ __launch_bounds__(256) void k_scan1(int* __restrict__ data, int n,
                                               int* __restrict__ blksum) {
  __shared__ int sh[256];
  int t = threadIdx.x;
  int base = blockIdx.x * 1024 + t * 4;
  int v0 = (base + 0 < n) ? data[base + 0] : 0;
  int v1 = (base + 1 < n) ? data[base + 1] : 0;
  int v2 = (base + 2 < n) ? data[base + 2] : 0;
  int v3 = (base + 3 < n) ? data[base + 3] : 0;
  v1 += v0; v2 += v1; v3 += v2;
  int tot = v3;
  sh[t] = tot;
  __syncthreads();
  for (int o = 1; o < 256; o <<= 1) {
    int x = (t >= o) ? sh[t - o] : 0;
    __syncthreads();
    sh[t] += x;
    __syncthreads();
  }
  int excl = sh[t] - tot;
  if (base + 0 < n) data[base + 0] = v0 + excl;
  if (base + 1 < n) data[base + 1] = v1 + excl;
  if (base + 2 < n) data[base + 2] = v2 + excl;
  if (base + 3 < n) data[base + 3] = v3 + excl;
  if (t == 255) blksum[blockIdx.x] = sh[255];
}

__global__ __launch_bounds__(256) void k_scan2(int* __restrict__ blksum, int nb) {
  __shared__ int sh[256];
  int t = threadIdx.x;
  sh[t] = (t < nb) ? blksum[t] : 0;
  __syncthreads();
  for (int o = 1; o < 256; o <<= 1) {
    int x = (t >= o) ? sh[t - o] : 0;
    __syncthreads();
    sh[t] += x;
    __syncthreads();
  }
  if (t < nb) blksum[t] = sh[t];
}

__global__ __launch_bounds__(256) void k_scan3(int* __restrict__ data, int n,
                                               const int* __restrict__ blksum) {
  int b = blockIdx.x;
  if (b == 0) return;
  int add = blksum[b - 1];
  int base = b * 1024 + threadIdx.x * 4;
  for (int j = 0; j < 4; ++j)
    if (base + j < n) data[base + j] += add;
}

// scatter src VALUES into dst-CSR segments (order fixed by the sort below)
__global__ __launch_bounds__(256) void k_scatter(const int* __restrict__ dst,
                                                 const int* __restrict__ src,
                                                 const int* __restrict__ off,
                                                 int* __restrict__ cursor,
                                                 int* __restrict__ srcs) {
  int e = blockIdx.x * 256 + threadIdx.x;
  if (e >= N_EDGES) return;
  int d = dst[e];
  int pos = off[d] + atomicAdd(&cursor[d], 1);
  srcs[pos] = src[e];
}

// sort src values within each segment -> deterministic accumulation order
__global__ __launch_bounds__(256) void k_sortseg(const int* __restrict__ off,
                                                 int* __restrict__ srcs) {
  int n = blockIdx.x * 256 + threadIdx.x;
  if (n >= N_NODES) return;
  int beg = off[n], end = off[n + 1];
  for (int i = beg + 1; i < end; ++i) {
    int key = srcs[i];
    int j = i - 1;
    while (j >= beg && srcs[j] > key) { srcs[j + 1] = srcs[j]; --j; }
    srcs[j + 1] = key;
  }
}

// ---------------------------------------------------------------- encoder
__global__ __launch_bounds__(256) void k_encoder(const float* __restrict__ nf,
                                                 const float* __restrict__ W,
                                                 const float* __restrict__ b,
                                                 ushort* __restrict__ hb) {
  __shared__ float Ws[F_IN * HID];
  int t = threadIdx.x;
  for (int i = t; i < F_IN * HID; i += 256) Ws[i] = W[i];
  __syncthreads();
  int idx = blockIdx.x * 256 + t;
  int n = idx >> 6;
  int c = idx & 63;
  if (n >= N_NODES) return;
  float acc = b[c];
  const float* row = nf + (size_t)n * F_IN;
  for (int k = 0; k < F_IN; ++k) acc = fmaf(row[k], Ws[k * HID + c], acc);
  hb[(size_t)n * HID + c] = f2bf(acc);
}

// ----------------------------------------------- W[K,256] -> Wt[256,K] bf16
template <int K>
__global__ __launch_bounds__(256) void k_wt(const float* __restrict__ W,
                                            ushort* __restrict__ Wt) {
  int idx = blockIdx.x * 256 + threadIdx.x;
  if (idx >= K * HID4) return;
  int k = idx >> 8;
  int n = idx & 255;
  Wt[(size_t)n * K + k] = f2bf(W[idx]);
}

// ---------------------------------------------------------- bf16 MFMA GEMM
// Cb[n_rows,256] (bf16) = A[n_rows,K] (bf16) @ Wt[256,K]^T (bf16)
// fused epilogue: el[row,h]/er[row,h] computed fp32-exact (each 64-col
// quarter of the tile is exactly one head).
template <int K>
__global__ __launch_bounds__(256) void k_gemm_mfma(const ushort* __restrict__ A,
                                                   const ushort* __restrict__ Bt,
                                                   ushort* __restrict__ Cb,
                                                   const float* __restrict__ al,
                                                   const float* __restrict__ ar,
                                                   float* __restrict__ el,
                                                   float* __restrict__ er,
                                                   int n_rows) {
  __shared__ ushort As[128][40];  // [row][k], +8 pad
  __shared__ ushort Bs[128][40];  // [col][k], +8 pad
  int t = threadIdx.x;
  int lane = t & 63;
  int wid = t >> 6;
  int wr = wid >> 1, wc = wid & 1;  // 2x2 waves, each 64x64
  int brow = blockIdx.x * 128;
  int bcol = blockIdx.y * 128;

  f32x4 acc[4][4];
#pragma unroll
  for (int m = 0; m < 4; ++m)
#pragma unroll
    for (int n = 0; n < 4; ++n) acc[m][n] = (f32x4)(0.f);

  int srow = t >> 2;
  int soff = (t & 3) * 8;
  int fr = lane & 15;
  int ko = (lane >> 4) * 8;

  for (int k0 = 0; k0 < K; k0 += 32) {
    {
      int gr0 = brow + srow, gr1 = gr0 + 64;
      int4 z4 = make_int4(0, 0, 0, 0);
      int4 va0 = (gr0 < n_rows) ? *(const int4*)(A + (size_t)gr0 * K + k0 + soff) : z4;
      int4 va1 = (gr1 < n_rows) ? *(const int4*)(A + (size_t)gr1 * K + k0 + soff) : z4;
      int4 vb0 = *(const int4*)(Bt + (size_t)(bcol + srow) * K + k0 + soff);
      int4 vb1 = *(const int4*)(Bt + (size_t)(bcol + srow + 64) * K + k0 + soff);
      *(int4*)&As[srow][soff] = va0;
      *(int4*)&As[srow + 64][soff] = va1;
      *(int4*)&Bs[srow][soff] = vb0;
      *(int4*)&Bs[srow + 64][soff] = vb1;
    }
    __syncthreads();
    short8 a[4], b[4];
#pragma unroll
    for (int m = 0; m < 4; ++m) a[m] = *(const short8*)&As[wr * 64 + m * 16 + fr][ko];
#pragma unroll
    for (int n = 0; n < 4; ++n) b[n] = *(const short8*)&Bs[wc * 64 + n * 16 + fr][ko];
#pragma unroll
    for (int m = 0; m < 4; ++m)
#pragma unroll
      for (int n = 0; n < 4; ++n)
        acc[m][n] = __builtin_amdgcn_mfma_f32_16x16x32_bf16(a[m], b[n], acc[m][n], 0, 0, 0);
    __syncthreads();
  }

  int r0 = (lane >> 4) * 4;
  int cc = lane & 15;
  int q = blockIdx.y * 2 + wc;  // head index of this 64-col quarter
  float alr[4], arr[4];
#pragma unroll
  for (int n = 0; n < 4; ++n) {
    int col = bcol + wc * 64 + n * 16 + cc;
    alr[n] = al[col];
    arr[n] = ar[col];
  }
#pragma unroll
  for (int m = 0; m < 4; ++m) {
#pragma unroll
    for (int j = 0; j < 4; ++j) {
      float pl = 0.f, pr = 0.f;
#pragma unroll
      for (int n = 0; n < 4; ++n) {
        pl = fmaf(acc[m][n][j], alr[n], pl);
        pr = fmaf(acc[m][n][j], arr[n], pr);
      }
#pragma unroll
      for (int o = 1; o < 16; o <<= 1) {
        pl += __shfl_xor(pl, o, 64);
        pr += __shfl_xor(pr, o, 64);
      }
      int row = brow + wr * 64 + m * 16 + r0 + j;
      if (row >= n_rows) continue;
      if (cc == 0) {
        el[(size_t)row * NHEAD + q] = pl;
        er[(size_t)row * NHEAD + q] = pr;
      }
#pragma unroll
      for (int n = 0; n < 4; ++n)
        Cb[(size_t)row * HID4 + bcol + wc * 64 + n * 16 + cc] = f2bf(acc[m][n][j]);
    }
  }
}

// ------------------------------------------------- fused edge softmax + agg
__global__ __launch_bounds__(256) void k_agg(const ushort* __restrict__ zb,
                                             const float* __restrict__ el,
                                             const float* __restrict__ er,
                                             const int* __restrict__ off,
                                             const int* __restrict__ srcs,
                                             const float* __restrict__ bias,
                                             ushort* __restrict__ outb) {
  int n = (blockIdx.x * 256 + threadIdx.x) >> 6;  // one wave per dst node
  int lane = threadIdx.x & 63;
  if (n >= N_NODES) return;
  int h = lane >> 4;
  int c = lane * 4;
  int beg = off[n], end = off[n + 1];
  float erh = er[(size_t)n * NHEAD + h];
  float m = -1e30f, s = 0.f;
  float a0 = 0.f, a1 = 0.f, a2 = 0.f, a3 = 0.f;

  int sn_n = 0;
  float el_n = 0.f;
  ushort4 z_n = make_ushort4(0, 0, 0, 0);
  if (beg < end) {
    sn_n = srcs[beg];
    el_n = el[(size_t)sn_n * NHEAD + h];
    z_n = *(const ushort4*)(zb + (size_t)sn_n * HID4 + c);
  }
  for (int p = beg; p < end; ++p) {
    float elv = el_n;
    ushort4 zv = z_n;
    if (p + 1 < end) {  // lookahead: issue next edge's loads before compute
      int sn2 = srcs[p + 1];
      el_n = el[(size_t)sn2 * NHEAD + h];
      z_n = *(const ushort4*)(zb + (size_t)sn2 * HID4 + c);
    }
    float eh = elv + erh;
    eh = eh >= 0.f ? eh : 0.2f * eh;
    float nm = fmaxf(m, eh);
    float sc = __expf(m - nm);
    float pe = __expf(eh - nm);
    s = s * sc + pe;
    a0 = a0 * sc + pe * bf2f(zv.x);
    a1 = a1 * sc + pe * bf2f(zv.y);
    a2 = a2 * sc + pe * bf2f(zv.z);
    a3 = a3 * sc + pe * bf2f(zv.w);
    m = nm;
  }
  float inv = (s > 0.f) ? 1.f / s : 0.f;
  float4 b4 = *(const float4*)(bias + c);
  ushort4 o;
  o.x = f2bf(fmaxf(a0 * inv + b4.x, 0.f));
  o.y = f2bf(fmaxf(a1 * inv + b4.y, 0.f));
  o.z = f2bf(fmaxf(a2 * inv + b4.z, 0.f));
  o.w = f2bf(fmaxf(a3 * inv + b4.w, 0.f));
  *(ushort4*)(outb + (size_t)n * HID4 + c) = o;
}

// ---------------------------------------------------------------- readout
__global__ __launch_bounds__(256) void k_pool_mlp(const ushort* __restrict__ h,
                                                  const float* __restrict__ r1W,
                                                  const float* __restrict__ r1b,
                                                  const float* __restrict__ r2W,
                                                  const float* __restrict__ r2b,
                                                  float* __restrict__ out) {
  __shared__ float pooled[3 * HID4];
  __shared__ float part[4][HID];
  __shared__ float mid[HID];
  int g = blockIdx.x;
  int t = threadIdx.x;
  const ushort* base = h + (size_t)g * NODES_PER_G * HID4;
  float sum = 0.f, mx = -1e30f;
  for (int i = 0; i < NODES_PER_G; ++i) {
    float v = bf2f(base[(size_t)i * HID4 + t]);
    sum += v;
    mx = fmaxf(mx, v);
  }
  pooled[t] = sum / (float)NODES_PER_G;
  pooled[HID4 + t] = mx;
  pooled[2 * HID4 + t] = sum;
  __syncthreads();
  {
    int o = t & 63, chunk = t >> 6;
    float acc = 0.f;
    int k0 = chunk * 192;
    for (int k = k0; k < k0 + 192; ++k) acc = fmaf(pooled[k], r1W[k * HID + o], acc);
    part[chunk][o] = acc;
  }
  __syncthreads();
  if (t < HID) {
    float acc = r1b[t] + part[0][t] + part[1][t] + part[2][t] + part[3][t];
    mid[t] = fmaxf(acc, 0.f);
  }
  __syncthreads();
  if (t < OUT_DIM) {
    float acc = r2b[t];
    for (int k = 0; k < HID; ++k) acc = fmaf(mid[k], r2W[k * OUT_DIM + t], acc);
    out[(size_t)g * OUT_DIM + t] = acc;
  }
}

// ---------------------------------------------------------------- launch
extern "C" void kernel_launch(void* const* d_in, const int* in_sizes, int n_in,
                              void* d_out, int out_size, void* d_ws, size_t ws_size,
                              hipStream_t stream) {
  const float* node_feat = (const float*)d_in[0];
  const int* src = (const int*)d_in[1];
  const int* dst = (const int*)d_in[2];
  const float* enc_W = (const float*)d_in[4];
  const float* enc_b = (const float*)d_in[5];
  const float* Wl[3] = {(const float*)d_in[6], (const float*)d_in[10], (const float*)d_in[14]};
  const float* all[3] = {(const float*)d_in[7], (const float*)d_in[11], (const float*)d_in[15]};
  const float* arl[3] = {(const float*)d_in[8], (const float*)d_in[12], (const float*)d_in[16]};
  const float* bl[3] = {(const float*)d_in[9], (const float*)d_in[13], (const float*)d_in[17]};
  const float* r1W = (const float*)d_in[18];
  const float* r1b = (const float*)d_in[19];
  const float* r2W = (const float*)d_in[20];
  const float* r2b = (const float*)d_in[21];
  float* out = (float*)d_out;

  char* p = (char*)d_ws;
  auto alloc = [&](size_t bytes) {
    void* r = (void*)p;
    p += (bytes + 255) & ~(size_t)255;
    return r;
  };
  int* off = (int*)alloc((N_NODES + 1) * sizeof(int));
  int* cursor = (int*)alloc(N_NODES * sizeof(int));
  int* srcs = (int*)alloc(N_EDGES * sizeof(int));
  int* blksum = (int*)alloc(256 * sizeof(int));
  float* el = (float*)alloc((size_t)N_NODES * NHEAD * sizeof(float));
  float* er = (float*)alloc((size_t)N_NODES * NHEAD * sizeof(float));
  ushort* Qb = (ushort*)alloc((size_t)N_NODES * HID4 * sizeof(ushort));  // z (bf16)
  ushort* Pb = (ushort*)alloc((size_t)N_NODES * HID4 * sizeof(ushort));  // h (bf16)
  ushort* Wt = (ushort*)alloc((size_t)HID4 * HID4 * sizeof(ushort));     // W^T bf16

  // ---- CSR build (deterministic via per-segment value sort)
  hipMemsetAsync(off, 0, (N_NODES + 1) * sizeof(int), stream);
  hipMemsetAsync(cursor, 0, N_NODES * sizeof(int), stream);
  k_count<<<(N_EDGES + 255) / 256, 256, 0, stream>>>(dst, off);
  const int SCAN_N = N_NODES + 1;
  const int NB = (SCAN_N + 1023) / 1024;
  k_scan1<<<NB, 256, 0, stream>>>(off, SCAN_N, blksum);
  k_scan2<<<1, 256, 0, stream>>>(blksum, NB);
  k_scan3<<<NB, 256, 0, stream>>>(off, SCAN_N, blksum);
  k_scatter<<<(N_EDGES + 255) / 256, 256, 0, stream>>>(dst, src, off, cursor, srcs);
  k_sortseg<<<(N_NODES + 255) / 256, 256, 0, stream>>>(off, srcs);

  // ---- encoder -> Pb (bf16)
  k_encoder<<<((size_t)N_NODES * HID + 255) / 256, 256, 0, stream>>>(node_feat, enc_W, enc_b, Pb);

  // ---- 3 GAT layers: GEMM+el/er (Pb -> Qb,el,er) ; agg (Qb -> Pb)
  dim3 ggrid((N_NODES + 127) / 128, HID4 / 128);
  for (int l = 0; l < 3; ++l) {
    if (l == 0) {
      k_wt<HID><<<(HID * HID4 + 255) / 256, 256, 0, stream>>>(Wl[0], Wt);
      k_gemm_mfma<HID><<<ggrid, 256, 0, stream>>>(Pb, Wt, Qb, all[0], arl[0], el, er, N_NODES);
    } else {
      k_wt<HID4><<<(HID4 * HID4 + 255) / 256, 256, 0, stream>>>(Wl[l], Wt);
      k_gemm_mfma<HID4><<<ggrid, 256, 0, stream>>>(Pb, Wt, Qb, all[l], arl[l], el, er, N_NODES);
    }
    k_agg<<<(N_NODES + 3) / 4, 256, 0, stream>>>(Qb, el, er, off, srcs, bl[l], Pb);
  }

  // ---- readout
  k_pool_mlp<<<N_GRAPHS, 256, 0, stream>>>(Pb, r1W, r1b, r2W, r2b, out);
}

// Round 5
// 454.355 us; speedup vs baseline: 1.9851x; 1.0927x over previous
//
#include <hip/hip_runtime.h>

#define N_NODES 100000
#define N_EDGES 400000
#define N_GRAPHS 2000
#define F_IN 74
#define ENC_KP 96
#define HID 64
#define NHEAD 4
#define HID4 256
#define OUT_DIM 128
#define NODES_PER_G 50

typedef __attribute__((ext_vector_type(8))) short short8;
typedef __attribute__((ext_vector_type(4))) float f32x4;

__device__ inline ushort f2bf(float f) {
  union { float f; unsigned u; } v; v.f = f;
  unsigned u = v.u;
  return (ushort)((u + 0x7FFFu + ((u >> 16) & 1u)) >> 16);
}
__device__ inline float bf2f(ushort b) {
  union { unsigned u; float f; } v; v.u = ((unsigned)b) << 16;
  return v.f;
}

// ---------------------------------------------------------------- CSR build
__global__ __launch_bounds__(256) void k_count(const int* __restrict__ dst,
                                               int* __restrict__ off) {
  int e = blockIdx.x * 256 + threadIdx.x;
  if (e < N_EDGES) atomicAdd(&off[dst[e] + 1], 1);
}

__global__ __launch_bounds__(256) void k_scan1(int* __restrict__ data, int n,
                                               int* __restrict__ blksum) {
  __shared__ int sh[256];
  int t = threadIdx.x;
  int base = blockIdx.x * 1024 + t * 4;
  int v0 = (base + 0 < n) ? data[base + 0] : 0;
  int v1 = (base + 1 < n) ? data[base + 1] : 0;
  int v2 = (base + 2 < n) ? data[base + 2] : 0;
  int v3 = (base + 3 < n) ? data[base + 3] : 0;
  v1 += v0; v2 += v1; v3 += v2;
  int tot = v3;
  sh[t] = tot;
  __syncthreads();
  for (int o = 1; o < 256; o <<= 1) {
    int x = (t >= o) ? sh[t - o] : 0;
    __syncthreads();
    sh[t] += x;
    __syncthreads();
  }
  int excl = sh[t] - tot;
  if (base + 0 < n) data[base + 0] = v0 + excl;
  if (base + 1 < n) data[base + 1] = v1 + excl;
  if (base + 2 < n) data[base + 2] = v2 + excl;
  if (base + 3 < n) data[base + 3] = v3 + excl;
  if (t == 255) blksum[blockIdx.x] = sh[255];
}

__global__ __launch_bounds__(256) void k_scan2(int* __restrict__ blksum, int nb) {
  __shared__ int sh[256];
  int t = threadIdx.x;
  sh[t] = (t < nb) ? blksum[t] : 0;
  __syncthreads();
  for (int o = 1; o < 256; o <<= 1) {
    int x = (t >= o) ? sh[t - o] : 0;
    __syncthreads();
    sh[t] += x;
    __syncthreads();
  }
  if (t < nb) blksum[t] = sh[t];
}

__global__ __launch_bounds__(256) void k_scan3(int* __restrict__ data, int n,
                                               const int* __restrict__ blksum) {
  int b = blockIdx.x;
  if (b == 0) return;
  int add = blksum[b - 1];
  int base = b * 1024 + threadIdx.x * 4;
  for (int j = 0; j < 4; ++j)
    if (base + j < n) data[base + j] += add;
}

__global__ __launch_bounds__(256) void k_scatter(const int* __restrict__ dst,
                                                 const int* __restrict__ src,
                                                 const int* __restrict__ off,
                                                 int* __restrict__ cursor,
                                                 int* __restrict__ srcs) {
  int e = blockIdx.x * 256 + threadIdx.x;
  if (e >= N_EDGES) return;
  int d = dst[e];
  int pos = off[d] + atomicAdd(&cursor[d], 1);
  srcs[pos] = src[e];
}

__global__ __launch_bounds__(256) void k_sortseg(const int* __restrict__ off,
                                                 int* __restrict__ srcs) {
  int n = blockIdx.x * 256 + threadIdx.x;
  if (n >= N_NODES) return;
  int beg = off[n], end = off[n + 1];
  for (int i = beg + 1; i < end; ++i) {
    int key = srcs[i];
    int j = i - 1;
    while (j >= beg && srcs[j] > key) { srcs[j + 1] = srcs[j]; --j; }
    srcs[j + 1] = key;
  }
}

// -------------------------------------------- nf fp32 [N,74] -> bf16 [N,96]
__global__ __launch_bounds__(256) void k_pad_nf(const float* __restrict__ nf,
                                                ushort* __restrict__ nfb) {
  long long idx = (long long)blockIdx.x * 256 + threadIdx.x;
  if (idx >= (long long)N_NODES * ENC_KP) return;
  int n = (int)(idx / ENC_KP);
  int c = (int)(idx - (long long)n * ENC_KP);
  ushort v = 0;
  if (c < F_IN) v = f2bf(nf[(size_t)n * F_IN + c]);
  nfb[idx] = v;
}

// enc_W [74,64] fp32 -> Wte [64,96] bf16 (transposed, zero-padded)
__global__ __launch_bounds__(256) void k_wt_enc(const float* __restrict__ W,
                                                ushort* __restrict__ Wte) {
  int idx = blockIdx.x * 256 + threadIdx.x;
  if (idx >= HID * ENC_KP) return;
  int col = idx / ENC_KP;
  int k = idx - col * ENC_KP;
  ushort v = 0;
  if (k < F_IN) v = f2bf(W[(size_t)k * HID + col]);
  Wte[idx] = v;
}

// ------------------------------------------------------ encoder MFMA GEMM
// Pb[N,64] (bf16) = nfb[N,96] @ Wte[64,96]^T + enc_b
__global__ __launch_bounds__(256) void k_enc_mfma(const ushort* __restrict__ A,
                                                  const ushort* __restrict__ Bt,
                                                  const float* __restrict__ bias,
                                                  ushort* __restrict__ Cb) {
  __shared__ ushort As[128][104];  // stride 104 -> banks spread
  __shared__ ushort Bs[64][104];
  int t = threadIdx.x;
  int lane = t & 63;
  int wid = t >> 6;
  int brow = blockIdx.x * 128;

  // stage A: 2 threads per row, each covers 48 ushorts = 6 x int4
  {
    int r = t >> 1;
    int o = (t & 1) * 48;
    int gr = brow + r;
    const ushort* srcp = A + (size_t)gr * ENC_KP + o;
#pragma unroll
    for (int i = 0; i < 6; ++i) {
      int4 v = make_int4(0, 0, 0, 0);
      if (gr < N_NODES) v = *(const int4*)(srcp + i * 8);
      *(int4*)&As[r][o + i * 8] = v;
    }
  }
  // stage B: 64 rows, 2 threads per row, 48 ushorts each
  if (t < 128) {
    int r = t >> 1;
    int o = (t & 1) * 48;
#pragma unroll
    for (int i = 0; i < 6; ++i)
      *(int4*)&Bs[r][o + i * 8] = *(const int4*)(Bt + (size_t)r * ENC_KP + o + i * 8);
  }
  __syncthreads();

  int fr = lane & 15;
  int ko = (lane >> 4) * 8;
  f32x4 acc[2][4];
#pragma unroll
  for (int m = 0; m < 2; ++m)
#pragma unroll
    for (int n = 0; n < 4; ++n) acc[m][n] = (f32x4)(0.f);

#pragma unroll
  for (int ks = 0; ks < 3; ++ks) {
    short8 a[2], b[4];
#pragma unroll
    for (int m = 0; m < 2; ++m) a[m] = *(const short8*)&As[wid * 32 + m * 16 + fr][ks * 32 + ko];
#pragma unroll
    for (int n = 0; n < 4; ++n) b[n] = *(const short8*)&Bs[n * 16 + fr][ks * 32 + ko];
#pragma unroll
    for (int m = 0; m < 2; ++m)
#pragma unroll
      for (int n = 0; n < 4; ++n)
        acc[m][n] = __builtin_amdgcn_mfma_f32_16x16x32_bf16(a[m], b[n], acc[m][n], 0, 0, 0);
  }

  int r0 = (lane >> 4) * 4;
  int cc = lane & 15;
#pragma unroll
  for (int m = 0; m < 2; ++m) {
#pragma unroll
    for (int j = 0; j < 4; ++j) {
      int row = brow + wid * 32 + m * 16 + r0 + j;
      if (row >= N_NODES) continue;
#pragma unroll
      for (int n = 0; n < 4; ++n) {
        int col = n * 16 + cc;
        Cb[(size_t)row * HID + col] = f2bf(acc[m][n][j] + bias[col]);
      }
    }
  }
}

// ----------------------------------------------- W[K,256] -> Wt[256,K] bf16
template <int K>
__global__ __launch_bounds__(256) void k_wt(const float* __restrict__ W,
                                            ushort* __restrict__ Wt) {
  int idx = blockIdx.x * 256 + threadIdx.x;
  if (idx >= K * HID4) return;
  int k = idx >> 8;
  int n = idx & 255;
  Wt[(size_t)n * K + k] = f2bf(W[idx]);
}

// ---------------------------------------------------------- bf16 MFMA GEMM
template <int K>
__global__ __launch_bounds__(256) void k_gemm_mfma(const ushort* __restrict__ A,
                                                   const ushort* __restrict__ Bt,
                                                   ushort* __restrict__ Cb,
                                                   const float* __restrict__ al,
                                                   const float* __restrict__ ar,
                                                   float* __restrict__ el,
                                                   float* __restrict__ er,
                                                   int n_rows) {
  __shared__ ushort As[128][40];
  __shared__ ushort Bs[128][40];
  int t = threadIdx.x;
  int lane = t & 63;
  int wid = t >> 6;
  int wr = wid >> 1, wc = wid & 1;
  int brow = blockIdx.x * 128;
  int bcol = blockIdx.y * 128;

  f32x4 acc[4][4];
#pragma unroll
  for (int m = 0; m < 4; ++m)
#pragma unroll
    for (int n = 0; n < 4; ++n) acc[m][n] = (f32x4)(0.f);

  int srow = t >> 2;
  int soff = (t & 3) * 8;
  int fr = lane & 15;
  int ko = (lane >> 4) * 8;

  for (int k0 = 0; k0 < K; k0 += 32) {
    {
      int gr0 = brow + srow, gr1 = gr0 + 64;
      int4 z4 = make_int4(0, 0, 0, 0);
      int4 va0 = (gr0 < n_rows) ? *(const int4*)(A + (size_t)gr0 * K + k0 + soff) : z4;
      int4 va1 = (gr1 < n_rows) ? *(const int4*)(A + (size_t)gr1 * K + k0 + soff) : z4;
      int4 vb0 = *(const int4*)(Bt + (size_t)(bcol + srow) * K + k0 + soff);
      int4 vb1 = *(const int4*)(Bt + (size_t)(bcol + srow + 64) * K + k0 + soff);
      *(int4*)&As[srow][soff] = va0;
      *(int4*)&As[srow + 64][soff] = va1;
      *(int4*)&Bs[srow][soff] = vb0;
      *(int4*)&Bs[srow + 64][soff] = vb1;
    }
    __syncthreads();
    short8 a[4], b[4];
#pragma unroll
    for (int m = 0; m < 4; ++m) a[m] = *(const short8*)&As[wr * 64 + m * 16 + fr][ko];
#pragma unroll
    for (int n = 0; n < 4; ++n) b[n] = *(const short8*)&Bs[wc * 64 + n * 16 + fr][ko];
#pragma unroll
    for (int m = 0; m < 4; ++m)
#pragma unroll
      for (int n = 0; n < 4; ++n)
        acc[m][n] = __builtin_amdgcn_mfma_f32_16x16x32_bf16(a[m], b[n], acc[m][n], 0, 0, 0);
    __syncthreads();
  }

  int r0 = (lane >> 4) * 4;
  int cc = lane & 15;
  int q = blockIdx.y * 2 + wc;
  float alr[4], arr[4];
#pragma unroll
  for (int n = 0; n < 4; ++n) {
    int col = bcol + wc * 64 + n * 16 + cc;
    alr[n] = al[col];
    arr[n] = ar[col];
  }
#pragma unroll
  for (int m = 0; m < 4; ++m) {
#pragma unroll
    for (int j = 0; j < 4; ++j) {
      float pl = 0.f, pr = 0.f;
#pragma unroll
      for (int n = 0; n < 4; ++n) {
        pl = fmaf(acc[m][n][j], alr[n], pl);
        pr = fmaf(acc[m][n][j], arr[n], pr);
      }
#pragma unroll
      for (int o = 1; o < 16; o <<= 1) {
        pl += __shfl_xor(pl, o, 64);
        pr += __shfl_xor(pr, o, 64);
      }
      int row = brow + wr * 64 + m * 16 + r0 + j;
      if (row >= n_rows) continue;
      if (cc == 0) {
        el[(size_t)row * NHEAD + q] = pl;
        er[(size_t)row * NHEAD + q] = pr;
      }
#pragma unroll
      for (int n = 0; n < 4; ++n)
        Cb[(size_t)row * HID4 + bcol + wc * 64 + n * 16 + cc] = f2bf(acc[m][n][j]);
    }
  }
}

// ------------------------------------------------- fused edge softmax + agg
__global__ __launch_bounds__(256) void k_agg(const ushort* __restrict__ zb,
                                             const float* __restrict__ el,
                                             const float* __restrict__ er,
                                             const int* __restrict__ off,
                                             const int* __restrict__ srcs,
                                             const float* __restrict__ bias,
                                             ushort* __restrict__ outb) {
  int n = (blockIdx.x * 256 + threadIdx.x) >> 6;
  int lane = threadIdx.x & 63;
  if (n >= N_NODES) return;
  int h = lane >> 4;
  int c = lane * 4;
  int beg = off[n], end = off[n + 1];
  float erh = er[(size_t)n * NHEAD + h];
  float m = -1e30f, s = 0.f;
  float a0 = 0.f, a1 = 0.f, a2 = 0.f, a3 = 0.f;

  int sn_n = 0;
  float el_n = 0.f;
  ushort4 z_n = make_ushort4(0, 0, 0, 0);
  if (beg < end) {
    sn_n = srcs[beg];
    el_n = el[(size_t)sn_n * NHEAD + h];
    z_n = *(const ushort4*)(zb + (size_t)sn_n * HID4 + c);
  }
  for (int p = beg; p < end; ++p) {
    float elv = el_n;
    ushort4 zv = z_n;
    if (p + 1 < end) {
      int sn2 = srcs[p + 1];
      el_n = el[(size_t)sn2 * NHEAD + h];
      z_n = *(const ushort4*)(zb + (size_t)sn2 * HID4 + c);
    }
    float eh = elv + erh;
    eh = eh >= 0.f ? eh : 0.2f * eh;
    float nm = fmaxf(m, eh);
    float sc = __expf(m - nm);
    float pe = __expf(eh - nm);
    s = s * sc + pe;
    a0 = a0 * sc + pe * bf2f(zv.x);
    a1 = a1 * sc + pe * bf2f(zv.y);
    a2 = a2 * sc + pe * bf2f(zv.z);
    a3 = a3 * sc + pe * bf2f(zv.w);
    m = nm;
  }
  float inv = (s > 0.f) ? 1.f / s : 0.f;
  float4 b4 = *(const float4*)(bias + c);
  ushort4 o;
  o.x = f2bf(fmaxf(a0 * inv + b4.x, 0.f));
  o.y = f2bf(fmaxf(a1 * inv + b4.y, 0.f));
  o.z = f2bf(fmaxf(a2 * inv + b4.z, 0.f));
  o.w = f2bf(fmaxf(a3 * inv + b4.w, 0.f));
  *(ushort4*)(outb + (size_t)n * HID4 + c) = o;
}

// ---------------------------------------------------------------- readout
__global__ __launch_bounds__(256) void k_pool_mlp(const ushort* __restrict__ h,
                                                  const float* __restrict__ r1W,
                                                  const float* __restrict__ r1b,
                                                  const float* __restrict__ r2W,
                                                  const float* __restrict__ r2b,
                                                  float* __restrict__ out) {
  __shared__ float pooled[3 * HID4];
  __shared__ float part[4][HID];
  __shared__ float mid[HID];
  int g = blockIdx.x;
  int t = threadIdx.x;
  const ushort* base = h + (size_t)g * NODES_PER_G * HID4;
  float sum = 0.f, mx = -1e30f;
  for (int i = 0; i < NODES_PER_G; ++i) {
    float v = bf2f(base[(size_t)i * HID4 + t]);
    sum += v;
    mx = fmaxf(mx, v);
  }
  pooled[t] = sum / (float)NODES_PER_G;
  pooled[HID4 + t] = mx;
  pooled[2 * HID4 + t] = sum;
  __syncthreads();
  {
    int o = t & 63, chunk = t >> 6;
    float acc = 0.f;
    int k0 = chunk * 192;
    for (int k = k0; k < k0 + 192; ++k) acc = fmaf(pooled[k], r1W[k * HID + o], acc);
    part[chunk][o] = acc;
  }
  __syncthreads();
  if (t < HID) {
    float acc = r1b[t] + part[0][t] + part[1][t] + part[2][t] + part[3][t];
    mid[t] = fmaxf(acc, 0.f);
  }
  __syncthreads();
  if (t < OUT_DIM) {
    float acc = r2b[t];
    for (int k = 0; k < HID; ++k) acc = fmaf(mid[k], r2W[k * OUT_DIM + t], acc);
    out[(size_t)g * OUT_DIM + t] = acc;
  }
}

// ---------------------------------------------------------------- launch
extern "C" void kernel_launch(void* const* d_in, const int* in_sizes, int n_in,
                              void* d_out, int out_size, void* d_ws, size_t ws_size,
                              hipStream_t stream) {
  const float* node_feat = (const float*)d_in[0];
  const int* src = (const int*)d_in[1];
  const int* dst = (const int*)d_in[2];
  const float* enc_W = (const float*)d_in[4];
  const float* enc_b = (const float*)d_in[5];
  const float* Wl[3] = {(const float*)d_in[6], (const float*)d_in[10], (const float*)d_in[14]};
  const float* all[3] = {(const float*)d_in[7], (const float*)d_in[11], (const float*)d_in[15]};
  const float* arl[3] = {(const float*)d_in[8], (const float*)d_in[12], (const float*)d_in[16]};
  const float* bl[3] = {(const float*)d_in[9], (const float*)d_in[13], (const float*)d_in[17]};
  const float* r1W = (const float*)d_in[18];
  const float* r1b = (const float*)d_in[19];
  const float* r2W = (const float*)d_in[20];
  const float* r2b = (const float*)d_in[21];
  float* out = (float*)d_out;

  char* p = (char*)d_ws;
  auto alloc = [&](size_t bytes) {
    void* r = (void*)p;
    p += (bytes + 255) & ~(size_t)255;
    return r;
  };
  int* off = (int*)alloc((N_NODES + 1) * sizeof(int));
  int* cursor = (int*)alloc(N_NODES * sizeof(int));
  int* srcs = (int*)alloc(N_EDGES * sizeof(int));
  int* blksum = (int*)alloc(256 * sizeof(int));
  float* el = (float*)alloc((size_t)N_NODES * NHEAD * sizeof(float));
  float* er = (float*)alloc((size_t)N_NODES * NHEAD * sizeof(float));
  ushort* Qb = (ushort*)alloc((size_t)N_NODES * HID4 * sizeof(ushort));   // z (bf16)
  ushort* Pb = (ushort*)alloc((size_t)N_NODES * HID4 * sizeof(ushort));   // h (bf16)
  ushort* Wt = (ushort*)alloc((size_t)HID4 * HID4 * sizeof(ushort));      // W^T bf16
  ushort* nfb = (ushort*)alloc((size_t)N_NODES * ENC_KP * sizeof(ushort));
  ushort* Wte = (ushort*)alloc((size_t)HID * ENC_KP * sizeof(ushort));

  // ---- CSR build (deterministic via per-segment value sort)
  hipMemsetAsync(off, 0, (N_NODES + 1) * sizeof(int), stream);
  hipMemsetAsync(cursor, 0, N_NODES * sizeof(int), stream);
  k_count<<<(N_EDGES + 255) / 256, 256, 0, stream>>>(dst, off);
  const int SCAN_N = N_NODES + 1;
  const int NB = (SCAN_N + 1023) / 1024;
  k_scan1<<<NB, 256, 0, stream>>>(off, SCAN_N, blksum);
  k_scan2<<<1, 256, 0, stream>>>(blksum, NB);
  k_scan3<<<NB, 256, 0, stream>>>(off, SCAN_N, blksum);
  k_scatter<<<(N_EDGES + 255) / 256, 256, 0, stream>>>(dst, src, off, cursor, srcs);
  k_sortseg<<<(N_NODES + 255) / 256, 256, 0, stream>>>(off, srcs);

  // ---- encoder: pad/convert then MFMA GEMM -> Pb (bf16)
  k_pad_nf<<<(int)(((long long)N_NODES * ENC_KP + 255) / 256), 256, 0, stream>>>(node_feat, nfb);
  k_wt_enc<<<(HID * ENC_KP + 255) / 256, 256, 0, stream>>>(enc_W, Wte);
  k_enc_mfma<<<(N_NODES + 127) / 128, 256, 0, stream>>>(nfb, Wte, enc_b, Pb);

  // ---- 3 GAT layers: GEMM+el/er (Pb -> Qb,el,er) ; agg (Qb -> Pb)
  dim3 ggrid((N_NODES + 127) / 128, HID4 / 128);
  for (int l = 0; l < 3; ++l) {
    if (l == 0) {
      k_wt<HID><<<(HID * HID4 + 255) / 256, 256, 0, stream>>>(Wl[0], Wt);
      k_gemm_mfma<HID><<<ggrid, 256, 0, stream>>>(Pb, Wt, Qb, all[0], arl[0], el, er, N_NODES);
    } else {
      k_wt<HID4><<<(HID4 * HID4 + 255) / 256, 256, 0, stream>>>(Wl[l], Wt);
      k_gemm_mfma<HID4><<<ggrid, 256, 0, stream>>>(Pb, Wt, Qb, all[l], arl[l], el, er, N_NODES);
    }
    k_agg<<<(N_NODES + 3) / 4, 256, 0, stream>>>(Qb, el, er, off, srcs, bl[l], Pb);
  }

  // ---- readout
  k_pool_mlp<<<N_GRAPHS, 256, 0, stream>>>(Pb, r1W, r1b, r2W, r2b, out);
}